// Round 3
// baseline (274.542 us; speedup 1.0000x reference)
//
#include <hip/hip_runtime.h>
#include <math.h>

// Sampler: B=256 rows, V=128256 vocab.
// out[b] = (T[b]==0) ? argmax(logits[b,:])
//                    : argmax(logits[b,:]/T[b] - log(-log1p(-noise[b,:])))
// Log-space Gumbel-max (softmax denom + row-max cancel), all in log2 so each
// log is one HW v_log_f32.
// R2 post-mortem: VALUBusy 14.6%, HBM 15% -> latency-bound, 1 float4-pair of
// MLP per wave. R3: manual unroll x4, all 8 loads issued before use.

constexpr int TPB = 1024;

__device__ __forceinline__ void amax_comb(float v, int i, float& bv, int& bi) {
    // np.argmax semantics: strictly greater wins; ties -> lowest index
    if (v > bv || (v == bv && i < bi)) { bv = v; bi = i; }
}

// key = l*c - log2(-log1p(-u)), c = invT/ln2.  Abs err ~1e-6, far below
// top-1/top-2 Gumbel key gaps.  u==0 -> en=0 -> -inf -> key=+inf, matching
// reference probs/0 = +inf (first-index tie-break both sides).
__device__ __forceinline__ float gumbel_key(float l, float u, float c) {
    // u >= 0.125: 1-u exact on the 2^-24 uniform grid, |log2(1-u)| >= 0.19
    const float w   = 1.0f - u;
    const float enw = __log2f(w) * -0.693147180559945f;   // -log(1-u)
    // u < 0.125: en/u = 1 + u/2 + u^2/3 + ... (trunc err < 6e-6 rel)
    float p = 0.16666667f;
    p = fmaf(p, u, 0.2f);
    p = fmaf(p, u, 0.25f);
    p = fmaf(p, u, 0.33333333f);
    p = fmaf(p, u, 0.5f);
    p = fmaf(p, u, 1.0f);
    const float en = (u < 0.125f) ? p * u : enw;
    return fmaf(l, c, -__log2f(en));
}

__device__ __forceinline__ void do4_sample(const float4& l, const float4& u,
                                           int base, float c,
                                           float& bv, int& bi) {
    const float k0 = gumbel_key(l.x, u.x, c);
    const float k1 = gumbel_key(l.y, u.y, c);
    const float k2 = gumbel_key(l.z, u.z, c);
    const float k3 = gumbel_key(l.w, u.w, c);
    // indices ascend within a thread -> strict > keeps lowest index
    if (k0 > bv) { bv = k0; bi = base;     }
    if (k1 > bv) { bv = k1; bi = base + 1; }
    if (k2 > bv) { bv = k2; bi = base + 2; }
    if (k3 > bv) { bv = k3; bi = base + 3; }
}

__device__ __forceinline__ void do4_greedy(const float4& l, int base,
                                           float& bv, int& bi) {
    if (l.x > bv) { bv = l.x; bi = base;     }
    if (l.y > bv) { bv = l.y; bi = base + 1; }
    if (l.z > bv) { bv = l.z; bi = base + 2; }
    if (l.w > bv) { bv = l.w; bi = base + 3; }
}

__global__ __launch_bounds__(TPB) void sampler_kernel(
    const float* __restrict__ logits,
    const float* __restrict__ temps,
    const float* __restrict__ noise,
    int* __restrict__ out, int V)
{
    const int b = blockIdx.x;
    const float temp = temps[b];
    const float4* __restrict__ lg4 = (const float4*)(logits + (size_t)b * V);
    const int V4 = V >> 2;            // 32064
    const int nFull = V4 / TPB;       // 31 full strided steps
    const int t = threadIdx.x;

    float bv = -INFINITY;
    int   bi = 0x7fffffff;

    if (temp == 0.0f) {
        int j = 0;
        for (; j + 4 <= nFull; j += 4) {
            const float4 l0 = lg4[t + (j + 0) * TPB];
            const float4 l1 = lg4[t + (j + 1) * TPB];
            const float4 l2 = lg4[t + (j + 2) * TPB];
            const float4 l3 = lg4[t + (j + 3) * TPB];
            do4_greedy(l0, (t + (j + 0) * TPB) << 2, bv, bi);
            do4_greedy(l1, (t + (j + 1) * TPB) << 2, bv, bi);
            do4_greedy(l2, (t + (j + 2) * TPB) << 2, bv, bi);
            do4_greedy(l3, (t + (j + 3) * TPB) << 2, bv, bi);
        }
        for (; j < nFull; ++j)
            do4_greedy(lg4[t + j * TPB], (t + j * TPB) << 2, bv, bi);
        const int f = t + nFull * TPB;
        if (f < V4) do4_greedy(lg4[f], f << 2, bv, bi);
    } else {
        const float c = (1.0f / temp) * 1.4426950408889634f;  // invT / ln2
        const float4* __restrict__ nz4 = (const float4*)(noise + (size_t)b * V);
        int j = 0;
        for (; j + 4 <= nFull; j += 4) {
            // issue all 8 loads before any use -> 8 KB in flight per wave
            const float4 l0 = lg4[t + (j + 0) * TPB];
            const float4 l1 = lg4[t + (j + 1) * TPB];
            const float4 l2 = lg4[t + (j + 2) * TPB];
            const float4 l3 = lg4[t + (j + 3) * TPB];
            const float4 u0 = nz4[t + (j + 0) * TPB];
            const float4 u1 = nz4[t + (j + 1) * TPB];
            const float4 u2 = nz4[t + (j + 2) * TPB];
            const float4 u3 = nz4[t + (j + 3) * TPB];
            do4_sample(l0, u0, (t + (j + 0) * TPB) << 2, c, bv, bi);
            do4_sample(l1, u1, (t + (j + 1) * TPB) << 2, c, bv, bi);
            do4_sample(l2, u2, (t + (j + 2) * TPB) << 2, c, bv, bi);
            do4_sample(l3, u3, (t + (j + 3) * TPB) << 2, c, bv, bi);
        }
        for (; j < nFull; ++j)
            do4_sample(lg4[t + j * TPB], nz4[t + j * TPB],
                       (t + j * TPB) << 2, c, bv, bi);
        const int f = t + nFull * TPB;
        if (f < V4) do4_sample(lg4[f], nz4[f], f << 2, c, bv, bi);
    }

    // wave (64-lane) shuffle reduction, lowest-index tie-break
    #pragma unroll
    for (int off = 32; off > 0; off >>= 1) {
        const float ov = __shfl_down(bv, off);
        const int   oi = __shfl_down(bi, off);
        amax_comb(ov, oi, bv, bi);
    }

    __shared__ float s_v[TPB / 64];
    __shared__ int   s_i[TPB / 64];
    const int lane = t & 63;
    const int wave = t >> 6;
    if (lane == 0) { s_v[wave] = bv; s_i[wave] = bi; }
    __syncthreads();
    if (t == 0) {
        #pragma unroll
        for (int w = 1; w < TPB / 64; ++w) amax_comb(s_v[w], s_i[w], bv, bi);
        out[b] = bi;
    }
}

extern "C" void kernel_launch(void* const* d_in, const int* in_sizes, int n_in,
                              void* d_out, int out_size, void* d_ws, size_t ws_size,
                              hipStream_t stream) {
    const float* logits = (const float*)d_in[0];   // [B, V] fp32
    const float* temps  = (const float*)d_in[1];   // [B]    fp32
    const float* noise  = (const float*)d_in[2];   // [B, V] fp32
    int* out = (int*)d_out;                        // [B]    int32
    const int B = in_sizes[1];
    const int V = in_sizes[0] / B;
    sampler_kernel<<<B, TPB, 0, stream>>>(logits, temps, noise, out, V);
}

// Round 4
// 274.383 us; speedup vs baseline: 1.0006x; 1.0006x over previous
//
#include <hip/hip_runtime.h>
#include <math.h>

// Sampler: B=256 rows, V=128256 vocab.
// out[b] = (T[b]==0) ? argmax(logits[b,:])
//                    : argmax(logits[b,:]/T[b] - log(-log1p(-noise[b,:])))
// Log-space Gumbel-max (softmax denom + row-max cancel), all in log2 so each
// log is one HW v_log_f32.
//
// R3 post-mortem: latency-bound. VGPR=32 proved the compiler sank batched
// loads back to their uses (no ILP); 1 block/CU capped TLP at 16 waves.
// R4: (a) 4 chunks/row -> 1024 blocks, launch_bounds(1024,8) -> 2 resident
// blocks/CU = 32 waves/CU; (b) prefetch distance 2 via loop-carried rotation
// (compiler cannot sink a load whose use is 2 iterations later);
// (c) two-phase argmax through d_ws.

constexpr int TPB = 1024;
constexpr int CHUNKS = 4;

__device__ __forceinline__ void amax_comb(float v, int i, float& bv, int& bi) {
    // np.argmax semantics: strictly greater wins; ties -> lowest index
    if (v > bv || (v == bv && i < bi)) { bv = v; bi = i; }
}

// key = l*c - log2(-log1p(-u)), c = invT/ln2.  Abs err ~1e-6, far below
// top-1/top-2 Gumbel key gaps.  u==0 -> en=0 -> -inf -> key=+inf, matching
// reference probs/0 = +inf (first-index tie-break both sides).
__device__ __forceinline__ float gumbel_key(float l, float u, float c) {
    // u >= 0.125: 1-u exact on the 2^-24 uniform grid, |log2(1-u)| >= 0.19
    const float w   = 1.0f - u;
    const float enw = __log2f(w) * -0.693147180559945f;   // -log(1-u)
    // u < 0.125: en/u = 1 + u/2 + u^2/3 + ... (trunc err < 6e-6 rel)
    float p = 0.16666667f;
    p = fmaf(p, u, 0.2f);
    p = fmaf(p, u, 0.25f);
    p = fmaf(p, u, 0.33333333f);
    p = fmaf(p, u, 0.5f);
    p = fmaf(p, u, 1.0f);
    const float en = (u < 0.125f) ? p * u : enw;
    return fmaf(l, c, -__log2f(en));
}

__global__ __launch_bounds__(TPB, 8) void sampler_phase1(
    const float* __restrict__ logits,
    const float* __restrict__ temps,
    const float* __restrict__ noise,
    float* __restrict__ ws_val,
    int* __restrict__ ws_idx, int V)
{
    const int chunk = blockIdx.x & (CHUNKS - 1);
    const int b     = blockIdx.x / CHUNKS;
    const int V4    = V >> 2;              // 32064
    const int V4c   = V4 / CHUNKS;         // 8016 (V divisible by 16)
    const int gbase = chunk * V4c;         // this chunk's first float4 index
    const float temp = temps[b];
    const float4* __restrict__ lg4 =
        (const float4*)(logits + (size_t)b * V) + gbase;
    const float4* __restrict__ nz4 =
        (const float4*)(noise + (size_t)b * V) + gbase;
    const int t = threadIdx.x;
    const int last = V4c - 1;

    float bv = -INFINITY;
    int   bi = 0x7fffffff;

    if (temp == 0.0f) {
        // Greedy: argmax of raw logits, no noise traffic.
        float4 A = lg4[min(t, last)];
        float4 Bq = lg4[min(t + TPB, last)];
        for (int j = 0; j * TPB < V4c; ++j) {
            const int f = t + j * TPB;
            const float4 l = A;
            A = Bq;
            Bq = lg4[min(f + 2 * TPB, last)];   // consumed at j+2
            if (f < V4c) {
                const int base = (gbase + f) << 2;
                // per-thread indices ascend -> strict > keeps lowest index
                if (l.x > bv) { bv = l.x; bi = base;     }
                if (l.y > bv) { bv = l.y; bi = base + 1; }
                if (l.z > bv) { bv = l.z; bi = base + 2; }
                if (l.w > bv) { bv = l.w; bi = base + 3; }
            }
        }
    } else {
        const float c = (1.0f / temp) * 1.4426950408889634f;  // invT / ln2
        float4 La = lg4[min(t, last)],       Ua = nz4[min(t, last)];
        float4 Lb = lg4[min(t + TPB, last)], Ub = nz4[min(t + TPB, last)];
        for (int j = 0; j * TPB < V4c; ++j) {
            const int f = t + j * TPB;
            const float4 l = La, u = Ua;
            La = Lb; Ua = Ub;
            const int fn = min(f + 2 * TPB, last);
            Lb = lg4[fn]; Ub = nz4[fn];         // consumed at j+2
            if (f < V4c) {
                const int base = (gbase + f) << 2;
                const float k0 = gumbel_key(l.x, u.x, c);
                const float k1 = gumbel_key(l.y, u.y, c);
                const float k2 = gumbel_key(l.z, u.z, c);
                const float k3 = gumbel_key(l.w, u.w, c);
                if (k0 > bv) { bv = k0; bi = base;     }
                if (k1 > bv) { bv = k1; bi = base + 1; }
                if (k2 > bv) { bv = k2; bi = base + 2; }
                if (k3 > bv) { bv = k3; bi = base + 3; }
            }
        }
    }

    // wave (64-lane) shuffle reduction, lowest-index tie-break
    #pragma unroll
    for (int off = 32; off > 0; off >>= 1) {
        const float ov = __shfl_down(bv, off);
        const int   oi = __shfl_down(bi, off);
        amax_comb(ov, oi, bv, bi);
    }

    __shared__ float s_v[TPB / 64];
    __shared__ int   s_i[TPB / 64];
    const int lane = t & 63;
    const int wave = t >> 6;
    if (lane == 0) { s_v[wave] = bv; s_i[wave] = bi; }
    __syncthreads();
    if (t == 0) {
        #pragma unroll
        for (int w = 1; w < TPB / 64; ++w) amax_comb(s_v[w], s_i[w], bv, bi);
        ws_val[blockIdx.x] = bv;
        ws_idx[blockIdx.x] = bi;
    }
}

__global__ void sampler_phase2(const float* __restrict__ ws_val,
                               const int* __restrict__ ws_idx,
                               int* __restrict__ out, int B)
{
    const int b = blockIdx.x * blockDim.x + threadIdx.x;
    if (b >= B) return;
    float bv = -INFINITY;
    int   bi = 0x7fffffff;
    #pragma unroll
    for (int c = 0; c < CHUNKS; ++c) {
        const float v = ws_val[b * CHUNKS + c];
        const int   i = ws_idx[b * CHUNKS + c];
        // chunk-ascending iteration + strict-> keeps lowest index on ties
        if (v > bv || (v == bv && i < bi)) { bv = v; bi = i; }
    }
    out[b] = bi;
}

extern "C" void kernel_launch(void* const* d_in, const int* in_sizes, int n_in,
                              void* d_out, int out_size, void* d_ws, size_t ws_size,
                              hipStream_t stream) {
    const float* logits = (const float*)d_in[0];   // [B, V] fp32
    const float* temps  = (const float*)d_in[1];   // [B]    fp32
    const float* noise  = (const float*)d_in[2];   // [B, V] fp32
    int* out = (int*)d_out;                        // [B]    int32
    const int B = in_sizes[1];
    const int V = in_sizes[0] / B;

    float* ws_val = (float*)d_ws;                  // [B*CHUNKS]
    int*   ws_idx = (int*)d_ws + (size_t)B * CHUNKS;

    sampler_phase1<<<B * CHUNKS, TPB, 0, stream>>>(logits, temps, noise,
                                                   ws_val, ws_idx, V);
    sampler_phase2<<<(B + 255) / 256, 256, 0, stream>>>(ws_val, ws_idx, out, B);
}